// Round 5
// baseline (89.455 us; speedup 1.0000x reference)
//
#include <hip/hip_runtime.h>

#define LSZ 512
#define CCH 4
#define NLAY 4
#define TILE 64
#define HALO 8
#define RG  80          // logical region size = TILE + 2*HALO
#define RGP 82          // LDS row pitch: even (b64-aligned)
#define SLAB (156 * RGP)   // per-tile slab floats: B0 rows 0..79 + B1 rows 80..155
#define B1OFF (78 * RGP)   // logical B1 row i lives at slab + B1OFF + i*RGP (i in [2,77])
#define NT  1024        // 16 waves per stencil block

typedef float v2f __attribute__((ext_vector_type(2)));

__device__ __forceinline__ v2f pk_add(v2f a, v2f b) {
    v2f d; asm("v_pk_add_f32 %0, %1, %2" : "=v"(d) : "v"(a), "v"(b)); return d;
}
__device__ __forceinline__ v2f pk_mul(v2f a, v2f b) {
    v2f d; asm("v_pk_mul_f32 %0, %1, %2" : "=v"(d) : "v"(a), "v"(b)); return d;
}
__device__ __forceinline__ v2f pk_fma(v2f a, v2f b, v2f c) {
    v2f d; asm("v_pk_fma_f32 %0, %1, %2, %3" : "=v"(d) : "v"(a), "v"(b), "v"(c)); return d;
}
__device__ __forceinline__ v2f celu2(v2f y) {
    v2f r;
    r.x = y.x >= 0.0f ? y.x : __expf(y.x) - 1.0f;
    r.y = y.y >= 0.0f ? y.y : __expf(y.y) - 1.0f;
    return r;
}
// aligned 8B LDS load (even float index by construction)
__device__ __forceinline__ v2f ld2(const float* p) { return *(const v2f*)p; }

// Per-wave channel-uniformity check (true for this problem's inputs:
// w_self=ones, w_nbr=0.1*ones). Generic: if weights ever differ per channel,
// returns 0 and all channels compute fully.
__device__ __forceinline__ int weights_uniform(const float* __restrict__ w_self,
                                               const float* __restrict__ w_nbr)
{
    const int lane = threadIdx.x & 63;
    bool ok = true;
    if (lane < 12) {                       // w_self: (C,4), rows c=1..3 vs c=0
        int c = 1 + lane / 4, e = lane % 4;
        ok = (w_self[c * 4 + e] == w_self[e]);
    } else if (lane < 36) {                // w_nbr: (C,4,2), 24 pairs
        int u = lane - 12;
        int c = 1 + u / 8, r = u % 8;
        ok = (w_nbr[c * 8 + r] == w_nbr[r]);
    }
    unsigned long long vote = __ballot(ok);
    return vote == ~0ull ? 1 : 0;
}

// R5: multi-tile blocks. 576 (b, upper-tri tile) instances -> 256 blocks:
// blocks 0..63 take 3 tiles, blocks 64..255 take 2 (each tile in its own
// 156x82 LDS slab; 3 slabs + n-arrays = 159.3 KB, 1 block/CU, NT=1024).
// Rationale (R2/R3/R4 data): dbuf, B1-trim, occupancy 16->24 waves, and slot
// balance were ALL neutral -> stencil wall is per-phase dead time (barrier
// reconvergence + LDS latency), not unit throughput. Packing 2-3 tiles per
// block amortizes that dead time over ~2.5x more work per phase and cuts
// block-rounds/CU from ~2.25 to 1. Mixed 64x3+192x2 keeps the unit-bound
// worst case at 3 tiles/CU (same as before) while using all 256 CUs.
// Per-cell arithmetic, per-tile reduction order, FP groupings unchanged ->
// bitwise identical. x stays bitwise-symmetric, mirror-bin trick kept.
__global__ __launch_bounds__(NT, 4) void stencil_kernel(
    const float* __restrict__ nn,
    const float* __restrict__ w_self,
    const float* __restrict__ w_nbr,
    float* __restrict__ sep)
{
    __shared__ __align__(16) float buf[3 * SLAB];   // 153,504 B
    __shared__ float nrc[6][RG][3];                 // per tile: [2q]=nrow, [2q+1]=ncol

    const int tid = threadIdx.x;
    const int bid = blockIdx.x;
    const int uni = weights_uniform(w_self, w_nbr);
    const int ntl = bid < 64 ? 3 : 2;
    const int id0 = bid < 64 ? bid * 3 : 192 + (bid - 64) * 2;

    // per-tile metadata as scalars (runtime-q access via ternaries, no scratch)
    int bb0, bb1, bb2, gi0_0, gi0_1, gi0_2, gj0_0, gj0_1, gj0_2;
    int dd0, dd1, dd2; int tm0, tm1, tm2;
#pragma unroll
    for (int q = 0; q < 3; q++) {
        int id = id0 + (q < ntl ? q : 0);
        int b = id / 36;
        int t = id - b * 36;
        int ti = 0;
        while (t >= 8 - ti) { t -= 8 - ti; ti++; }
        int tj = ti + t;
        int gi0 = ti * TILE, gj0 = tj * TILE;
        int dd = (gj0 - gi0) & (LSZ - 1);
        int tm = (dd == 0) || (dd == 64) || (dd == 448);
        if (q == 0) { bb0 = b; gi0_0 = gi0; gj0_0 = gj0; dd0 = dd; tm0 = tm; }
        if (q == 1) { bb1 = b; gi0_1 = gi0; gj0_1 = gj0; dd1 = dd; tm1 = tm; }
        if (q == 2) { bb2 = b; gi0_2 = gi0; gj0_2 = gj0; dd2 = dd; tm2 = tm; }
    }

    // ---- load n rows & cols per tile (with halo, cyclic wrap) ----
    for (int u = tid; u < ntl * 480; u += NT) {
        int q = u / 480;
        int v = u - q * 480;
        int which = v >= 240 ? 1 : 0;
        int w2 = which ? v - 240 : v;
        int rr = w2 / 3, d = w2 - 3 * rr;
        int gb = which ? (q == 2 ? gj0_2 : (q == 1 ? gj0_1 : gj0_0))
                       : (q == 2 ? gi0_2 : (q == 1 ? gi0_1 : gi0_0));
        int b  = q == 2 ? bb2 : (q == 1 ? bb1 : bb0);
        int gl = (gb - HALO + rr) & (LSZ - 1);
        nrc[q * 2 + which][rr][d] = nn[(b * LSZ + gl) * 3 + d];
    }

    // ---- per-site slots: ntl*1600 sites over 1024 threads, 5 slots max ----
    int ofs[5], ring[5], ew[5], iv[5], jv[5], tl[5];
    const int total = ntl * 1600;
#pragma unroll
    for (int it = 0; it < 5; it++) {
        int base = it * NT;
        int rem = total - base;
        int g = -1;
        if (rem >= NT) g = base + tid;
        else if (rem > 0) {                 // partial slot: rem is a multiple of 64
            int per = rem >> 4;             // sites per wave (16 waves), <= 64
            int lane = tid & 63, wv = tid >> 6;
            if (lane < per) g = base + wv * per + lane;
        }
        if (g >= 0) {
            int q = g >= 3200 ? 2 : (g >= 1600 ? 1 : 0);
            int r = g - 1600 * q;
            int gi2 = r / 40;
            int i = 2 * gi2, j = 2 * (r - 40 * gi2);
            int dd = q == 2 ? dd2 : (q == 1 ? dd1 : dd0);
            int tm = q == 2 ? tm2 : (q == 1 ? tm1 : tm0);
            tl[it] = q; iv[it] = i; jv[it] = j;
            ofs[it] = q * SLAB + i * RGP + j;
            ring[it] = min(min(i, 78 - i), min(j, 78 - j));
            int e = (i - j - dd + 1) & 511;
            ew[it] = tm ? e : 99;           // 99: no diagonal masking applies
        } else { ofs[it] = -1; ring[it] = -1; ew[it] = 99; iv[it] = 0; jv[it] = 0; tl[it] = 0; }
    }
    __syncthreads();

    const int nch = uni ? 1 : CCH;
    for (int cc = 0; cc < nch; cc++) {
        // ---- build g (Gram, zero diagonal) into B0 of each slab ----
#pragma unroll
        for (int it = 0; it < 5; it++) {
            if (ofs[it] < 0) continue;
            int i = iv[it], j = jv[it], q2 = 2 * tl[it];
            float a00 = nrc[q2][i][0],   a01 = nrc[q2][i][1],   a02 = nrc[q2][i][2];
            float a10 = nrc[q2][i+1][0], a11 = nrc[q2][i+1][1], a12 = nrc[q2][i+1][2];
            float c00 = nrc[q2+1][j][0],   c01 = nrc[q2+1][j][1],   c02 = nrc[q2+1][j][2];
            float c10 = nrc[q2+1][j+1][0], c11 = nrc[q2+1][j+1][1], c12 = nrc[q2+1][j+1][2];
            float g00 = a00*c00 + a01*c01 + a02*c02;
            float g01 = a00*c10 + a01*c11 + a02*c12;
            float g10 = a10*c00 + a11*c01 + a12*c02;
            float g11 = a10*c10 + a11*c11 + a12*c12;
            if (ew[it] == 1) { g00 = 0.0f; g11 = 0.0f; }
            if (ew[it] == 2)   g01 = 0.0f;
            if (ew[it] == 0)   g10 = 0.0f;
            *(v2f*)&buf[ofs[it]]       = (v2f){g00, g01};
            *(v2f*)&buf[ofs[it] + RGP] = (v2f){g10, g11};
        }
        __syncthreads();

        // ---- 4 stencil layers, double-buffered per slab, 1 barrier/layer ----
        for (int ell = 0; ell < NLAY; ell++) {
            const float wsv = w_self[cc * NLAY + ell];
            const float wn1 = w_nbr[(cc * NLAY + ell) * 2 + 0];
            const float wn2 = w_nbr[(cc * NLAY + ell) * 2 + 1];
            const v2f ws2 = (v2f){wsv, wsv};
            const v2f w12 = (v2f){wn1, wn1};
            const v2f w22 = (v2f){wn2, wn2};
            const int pad  = 2 * (ell + 1);
            const int soff = (ell & 1) ? B1OFF : 0;
            const int doff = (ell & 1) ? 0 : B1OFF;
#pragma unroll
            for (int it = 0; it < 5; it++) {
                if (ring[it] < pad) continue;
                const float* P = buf + ofs[it] + soff;
                float*       D = buf + ofs[it] + doff;
                v2f cm2 = ld2(P - 2*RGP);
                v2f cm1 = ld2(P -   RGP);
                v2f c0  = ld2(P);
                v2f cp1 = ld2(P +   RGP);
                v2f cp2 = ld2(P + 2*RGP);
                v2f cp3 = ld2(P + 3*RGP);
                v2f A0  = ld2(P - 2);
                v2f C0  = ld2(P + 2);
                v2f A1  = ld2(P + RGP - 2);
                v2f C1  = ld2(P + RGP + 2);
                v2f s1a; s1a.x = A0.y + c0.y;  s1a.y = c0.x + C0.x;
                v2f s2a = pk_add(A0, C0);
                v2f v1a = pk_add(cm1, cp1);
                v2f v2a = pk_add(cm2, cp2);
                v2f ya = pk_fma(ws2, c0, pk_fma(w12, pk_add(s1a, v1a),
                                        pk_mul(w22, pk_add(s2a, v2a))));
                v2f s1b; s1b.x = A1.y + cp1.y; s1b.y = cp1.x + C1.x;
                v2f s2b = pk_add(A1, C1);
                v2f v1b = pk_add(c0,  cp2);
                v2f v2b = pk_add(cm1, cp3);
                v2f yb = pk_fma(ws2, cp1, pk_fma(w12, pk_add(s1b, v1b),
                                         pk_mul(w22, pk_add(s2b, v2b))));
                v2f xa = pk_add(c0,  celu2(ya));
                v2f xb = pk_add(cp1, celu2(yb));
                if (ew[it] == 1) { xa.x = 0.0f; xb.y = 0.0f; }
                if (ew[it] == 2)   xa.y = 0.0f;
                if (ew[it] == 0)   xb.x = 0.0f;
                *(v2f*)&D[0]   = xa;
                *(v2f*)&D[RGP] = xb;
            }
            __syncthreads();
        }
        // final x in B0 of each slab (core = [8,72)^2)

        // ---- cyclic-diagonal reduction: 127 diag x 4 parts per tile ----
        // pass 1: tile0 (tid<508) + tile1 (512<=tid<1020); pass 2: tile2
        {
            int q = -1, t0 = 0;
            if (tid < 508) { q = 0; t0 = tid; }
            else if (tid >= 512 && tid < 1020) { q = 1; t0 = tid - 512; }
            if (q >= 0) {
                int dt = t0 >> 2, part = t0 & 3;
                int delta = dt - 63;
                int ad = delta < 0 ? -delta : delta;
                int Nd = 64 - ad;
                int i0 = 8 + (delta < 0 ? -delta : 0);
                int base = q * SLAB + i0 * RGP + (i0 + delta);
                float s = 0.0f;
                for (int k = part; k < Nd; k += 4)
                    s += buf[base + k * (RGP + 1)];
                s += __shfl_xor(s, 1);
                s += __shfl_xor(s, 2);
                if (part == 0) {
                    int dd = q == 1 ? dd1 : dd0;
                    int b  = q == 1 ? bb1 : bb0;
                    int r = (dd + delta) & (LSZ - 1);
                    float* sp = sep + (b * CCH + cc) * LSZ;
                    atomicAdd(sp + r, s);
                    if (dd != 0)   // ti != tj: mirror bin for skipped transpose tile
                        atomicAdd(sp + ((LSZ - r) & (LSZ - 1)), s);
                }
            }
        }
        if (ntl == 3 && tid < 508) {
            int dt = tid >> 2, part = tid & 3;
            int delta = dt - 63;
            int ad = delta < 0 ? -delta : delta;
            int Nd = 64 - ad;
            int i0 = 8 + (delta < 0 ? -delta : 0);
            int base = 2 * SLAB + i0 * RGP + (i0 + delta);
            float s = 0.0f;
            for (int k = part; k < Nd; k += 4)
                s += buf[base + k * (RGP + 1)];
            s += __shfl_xor(s, 1);
            s += __shfl_xor(s, 2);
            if (part == 0) {
                int r = (dd2 + delta) & (LSZ - 1);
                float* sp = sep + (bb2 * CCH + cc) * LSZ;
                atomicAdd(sp + r, s);
                if (dd2 != 0)
                    atomicAdd(sp + ((LSZ - r) & (LSZ - 1)), s);
            }
        }
        if (cc + 1 < nch) __syncthreads();   // reductions read B0; next gram rewrites
    }
}

// MLP stage 1 (R0 arithmetic, bitwise identical). Channel-uniform sep reads
// remap to channel 0 via mask. Split mlp1/mlp2 kept: in-kernel cross-block
// handoff measured SLOWER via both __threadfence (R1: +40us, per-block L2
// writeback+invalidate) and agent-scope relaxed atomics (R3: ~+3us) than the
// ~2.5us a fused node saves. Stream ordering is the cheap mechanism.
__global__ __launch_bounds__(256) void mlp1_kernel(
    const float* __restrict__ sep,
    const float* __restrict__ W1,
    const float* __restrict__ w_self,
    const float* __restrict__ w_nbr,
    float* __restrict__ partial)
{
    __shared__ float4 red[4][64];
    const int uni = weights_uniform(w_self, w_nbr);
    const int mmask = uni ? (LSZ - 1) : (CCH * LSZ - 1);   // &2047 = identity
    const int b  = blockIdx.x >> 5;
    const int ms = blockIdx.x & 31;
    const int kq = threadIdx.x & 63;
    const int mq = threadIdx.x >> 6;
    const int m0 = ms * 64 + mq * 16;
    const float* sv = sep + b * (CCH * LSZ);
    const float* w  = W1 + m0 * 256 + kq * 4;
    float4 a0 = {0,0,0,0}, a1 = {0,0,0,0};
#pragma unroll
    for (int m = 0; m < 16; m += 2) {
        float4 w0 = *(const float4*)(w + (m)     * 256);
        float4 w1 = *(const float4*)(w + (m + 1) * 256);
        float s0 = sv[(m0 + m) & mmask], s1 = sv[(m0 + m + 1) & mmask];
        a0.x += s0 * w0.x; a0.y += s0 * w0.y; a0.z += s0 * w0.z; a0.w += s0 * w0.w;
        a1.x += s1 * w1.x; a1.y += s1 * w1.y; a1.z += s1 * w1.z; a1.w += s1 * w1.w;
    }
    float4 a;
    a.x = a0.x + a1.x; a.y = a0.y + a1.y; a.z = a0.z + a1.z; a.w = a0.w + a1.w;
    red[mq][kq] = a;
    __syncthreads();
    if (mq == 0) {
        float4 r0 = red[0][kq], r1 = red[1][kq], r2 = red[2][kq], r3 = red[3][kq];
        float4 o;
        o.x = (r0.x + r1.x) + (r2.x + r3.x);
        o.y = (r0.y + r1.y) + (r2.y + r3.y);
        o.z = (r0.z + r1.z) + (r2.z + r3.z);
        o.w = (r0.w + r1.w) + (r2.w + r3.w);
        *(float4*)&partial[(b * 32 + ms) * 256 + kq * 4] = o;
    }
}

// MLP stage 2 (R0 arithmetic, bitwise identical)
__global__ __launch_bounds__(256) void mlp2_kernel(
    const float* __restrict__ partial,
    const float* __restrict__ b1,
    const float* __restrict__ W2,
    const float* __restrict__ b2,
    float* __restrict__ out)
{
    __shared__ double red[4];
    const int b = blockIdx.x;
    const int k = threadIdx.x;
    double s = 0;
#pragma unroll
    for (int p = 0; p < 32; p++)
        s += (double)partial[(b * 32 + p) * 256 + k];
    s += (double)b1[k];
    s = s >= 0.0 ? s : exp(s) - 1.0;          // celu
    double q = s * (double)W2[k];
    for (int off = 32; off >= 1; off >>= 1) q += __shfl_down(q, off);
    if ((k & 63) == 0) red[k >> 6] = q;
    __syncthreads();
    if (k == 0) {
        double y = ((red[0] + red[1]) + (red[2] + red[3])) + (double)b2[0];
        out[b] = (float)exp(-y);
    }
}

extern "C" void kernel_launch(void* const* d_in, const int* in_sizes, int n_in,
                              void* d_out, int out_size, void* d_ws, size_t ws_size,
                              hipStream_t stream) {
    const float* nn     = (const float*)d_in[0];
    const float* w_self = (const float*)d_in[1];
    const float* w_nbr  = (const float*)d_in[2];
    const float* W1     = (const float*)d_in[3];
    const float* b1     = (const float*)d_in[4];
    const float* W2     = (const float*)d_in[5];
    const float* b2     = (const float*)d_in[6];
    float* out = (float*)d_out;
    float* sep     = (float*)d_ws;                                  // 128 KB
    float* partial = (float*)((char*)d_ws + 128 * 1024);            // 512 KB

    hipMemsetAsync(sep, 0, 16 * CCH * LSZ * sizeof(float), stream);
    stencil_kernel<<<256, NT, 0, stream>>>(nn, w_self, w_nbr, sep);
    mlp1_kernel<<<512, 256, 0, stream>>>(sep, W1, w_self, w_nbr, partial);
    mlp2_kernel<<<16, 256, 0, stream>>>(partial, b1, W2, b2, out);
}